// Round 7
// baseline (200.228 us; speedup 1.0000x reference)
//
#include <hip/hip_runtime.h>
#include <stdint.h>
#include <stddef.h>

#define S_LEN 2048
#define BATCH 2
#define HID 1024
#define NHEADS 16
#define HDIM 64

typedef __attribute__((ext_vector_type(8))) short short8;
typedef __attribute__((ext_vector_type(4))) short short4v;
typedef __attribute__((ext_vector_type(4))) float float4v;

#define MFMA32(a, b, c) __builtin_amdgcn_mfma_f32_16x16x32_bf16((a), (b), (c), 0, 0, 0)

#if __has_builtin(__builtin_amdgcn_mfma_f32_16x16x16_bf16)
#define MFMA16(a, b, c) __builtin_amdgcn_mfma_f32_16x16x16_bf16((a), (b), (c), 0, 0, 0)
#elif __has_builtin(__builtin_amdgcn_mfma_f32_16x16x16bf16_1k)
#define MFMA16(a, b, c) __builtin_amdgcn_mfma_f32_16x16x16bf16_1k((a), (b), (c), 0, 0, 0)
#else
static __device__ __forceinline__ float4v mfma16_asm(short4v a, short4v b, float4v c) {
  asm volatile("v_mfma_f32_16x16x16_bf16 %0, %1, %2, %0" : "+v"(c) : "v"(a), "v"(b));
  return c;
}
#define MFMA16(a, b, c) mfma16_asm((a), (b), (c))
#endif

#define SCALE_L2E 0.18033688011f  // log2(e)/8 — folded into K at GEMM epilogue

__device__ __forceinline__ short f2bf(float f) {
  union { float f; uint32_t u; } v; v.f = f;
  uint32_t u = v.u;
  uint32_t r = (u + 0x7fffu + ((u >> 16) & 1u)) >> 16;
  return (short)(uint16_t)r;
}

// pack 4 fp32 -> 4 bf16 (round-half-up, v_perm; A-frag k=quad*4+j order)
__device__ __forceinline__ short4v pack_bf16x4(float4v v) {
  union { short4v s; uint32_t u[2]; } U;
  U.u[0] = __builtin_amdgcn_perm(__float_as_uint(v[1]) + 0x8000u,
                                 __float_as_uint(v[0]) + 0x8000u, 0x07060302u);
  U.u[1] = __builtin_amdgcn_perm(__float_as_uint(v[3]) + 0x8000u,
                                 __float_as_uint(v[2]) + 0x8000u, 0x07060302u);
  return U.s;
}

__device__ __forceinline__ void gl_lds16(const void* g, void* l) {
  __builtin_amdgcn_global_load_lds((const __attribute__((address_space(1))) void*)g,
                                   (__attribute__((address_space(3))) void*)l,
                                   16, 0, 0);
}

// ---------------- prep: cast X to bf16 ----------------
__global__ __launch_bounds__(256) void prep_cast(const float* __restrict__ x,
                                                 short* __restrict__ xbf) {
  int gid = blockIdx.x * 256 + threadIdx.x;
  const float4v* src = (const float4v*)x;
  float4v v = src[gid];
  short4v o;
  o[0] = f2bf(v[0]); o[1] = f2bf(v[1]); o[2] = f2bf(v[2]); o[3] = f2bf(v[3]);
  ((short4v*)xbf)[gid] = o;
}

// ---------------- prep: mask compaction ----------------
// Masked keys (mask==1) get exp2-bias -14427 -> exp2 underflows to EXACTLY 0,
// contributing nothing. Compact the key axis: cidx[s] = s' (prefix index over
// unmasked) or -1; maskc[s'] = 0 for real keys, -14427 for s' >= nk; nkpad[b] =
// round64(nk) bounds the attn key loop (~half of 2048). K/V^T pad rows zeroed
// so pad keys give c = -14427 + 0 -> ev = 0 (no NaN from uninit workspace).
__global__ __launch_bounds__(256) void prep_idx(const int* __restrict__ mask,
                                                short* __restrict__ maskc,
                                                short* __restrict__ cidx,
                                                int* __restrict__ nkinfo,
                                                short* __restrict__ Kc,
                                                short* __restrict__ Vtc) {
  __shared__ int sc[256];
  const int t = threadIdx.x;
  const short neg = f2bf(-14426.9504f);
  for (int b = 0; b < BATCH; b++) {
    int m[8]; int lc = 0;
    const int* mb = mask + b * S_LEN + t * 8;
#pragma unroll
    for (int j = 0; j < 8; j++) { m[j] = mb[j]; lc += (m[j] == 0); }
    sc[t] = lc;
    __syncthreads();
#pragma unroll
    for (int off = 1; off < 256; off <<= 1) {
      int u = (t >= off) ? sc[t - off] : 0;
      int v = sc[t];
      __syncthreads();
      sc[t] = u + v;
      __syncthreads();
    }
    int excl = sc[t] - lc;
    int nk = sc[255];
    int nkpad = (nk + 63) & ~63;
    if (t == 0) nkinfo[b] = nkpad;
    int run = excl;
#pragma unroll
    for (int j = 0; j < 8; j++) {
      short v;
      if (m[j] == 0) { v = (short)run; maskc[b * S_LEN + run] = 0; run++; }
      else v = (short)-1;
      cidx[b * S_LEN + t * 8 + j] = v;
    }
    // bias for every compact slot >= nk is -14427 (covers pad + unused tail)
    for (int i = nk + t; i < S_LEN; i += 256) maskc[b * S_LEN + i] = neg;
    // zero K pad rows: (b,h,s',0..63), s' in [nk, nkpad)
    for (int p = t; p < NHEADS * 64; p += 256) {
      int hh = p >> 6, sp = nk + (p & 63);
      if (sp < nkpad) {
        short* dst = Kc + ((size_t)(b * NHEADS + hh) * S_LEN + sp) * HDIM;
#pragma unroll
        for (int c8 = 0; c8 < 8; c8++) *(short8*)(dst + c8 * 8) = (short8)0;
      }
    }
    // zero V^T pad cols: (b,h,d)*S_LEN + s', s' in [nk, nkpad)
    for (int p = t; p < NHEADS * HDIM; p += 256) {
      int hh = p >> 6, dd = p & 63;
      short* dst = Vtc + ((size_t)(b * NHEADS + hh) * HDIM + dd) * S_LEN;
      for (int sp = nk; sp < nkpad; sp++) dst[sp] = 0;
    }
    __syncthreads();
  }
}

// ---------------- prep: transpose+cast the four weight matrices ----------------
__global__ __launch_bounds__(256) void prep_transpose(const float* __restrict__ w0,
                                                      const float* __restrict__ w1,
                                                      const float* __restrict__ w2,
                                                      const float* __restrict__ w3,
                                                      short* __restrict__ wt) {
  __shared__ short lds[64 * 66];
  int z = blockIdx.z;
  const float* w = (z == 0) ? w0 : (z == 1) ? w1 : (z == 2) ? w2 : w3;
  short* out = wt + (size_t)z * HID * HID;
  int k0 = blockIdx.x * 64, n0 = blockIdx.y * 64;
  int lane = threadIdx.x & 63, wrp = threadIdx.x >> 6;
#pragma unroll
  for (int i = 0; i < 16; i++) {
    int rr = wrp + i * 4;
    lds[lane * 66 + rr] = f2bf(w[(size_t)(k0 + rr) * HID + n0 + lane]);
  }
  __syncthreads();
#pragma unroll
  for (int i = 0; i < 16; i++) {
    int nn = wrp + i * 4;
    out[(size_t)(n0 + nn) * HID + k0 + lane] = lds[nn * 66 + lane];
  }
}

// ---------------- GEMM: C[M x N] = A[M x K] * Bt[N x K]^T + bias ----------------
// mode 0: Q (bf16 [b,h,s,d]); mode 1: K pre-scaled by log2e/8, rows scattered to
// compact index s'=cidx[s] (masked rows dropped); mode 2: Vt (bf16 [b,h,d,s'],
// compacted columns via LDS transpose); mode 3: fp32 row-major.
// DBUF=true: raw-barrier double-buffer, counted vmcnt across the barrier
// (R5 A/B: single-buffer QKV = 70us vs DBUF ~45us).
#define VPS 136  // Vt epilogue LDS row stride (shorts): 272B, 16B-aligned
template <int BM, int BN, bool TRANS_EP, bool DBUF>
__global__ __launch_bounds__(256) void gemm_bt(const short* __restrict__ A,
                                               const short* __restrict__ WTbase,
                                               const float* __restrict__ bq,
                                               const float* __restrict__ bk,
                                               const float* __restrict__ bv,
                                               const float* __restrict__ bo,
                                               short* __restrict__ outQ,
                                               short* __restrict__ outK,
                                               short* __restrict__ outVt,
                                               float* __restrict__ outF,
                                               const short* __restrict__ cidx,
                                               int mode_base) {
  constexpr int RI = BM / 32;
  constexpr int RJ = BN / 32;
  constexpr int TILE = BM * 128 + BN * 128;  // one staging tile (A+B)
  constexpr int LSZ1 = DBUF ? TILE * 2 : TILE;
  constexpr int LSZ = (TRANS_EP && LSZ1 < 128 * VPS * 2) ? 128 * VPS * 2 : LSZ1;
  __shared__ __align__(16) char lds[LSZ];
  const int tid = threadIdx.x;
  const int lane = tid & 63, w = tid >> 6;
  const int wm = w & 1, wn = w >> 1;
  const int quad = lane >> 4, l15 = lane & 15;
  const int mode = mode_base + blockIdx.z;
  const short* Bt = WTbase + (size_t)mode * HID * HID;
  const float* bias = (mode == 0) ? bq : (mode == 1) ? bk : (mode == 2) ? bv : bo;
  const int m0 = blockIdx.x * BM, n0 = blockIdx.y * BN;

  float4v acc[RI][RJ];
#pragma unroll
  for (int i = 0; i < RI; i++)
#pragma unroll
    for (int j = 0; j < RJ; j++) acc[i][j] = (float4v)0.0f;

  // stage one 64-K tile (BM/32 + BN/32 gl_lds16 per thread)
  auto issue = [&](int k0, char* buf) {
#pragma unroll
    for (int inst = 0; inst < BM / 32; inst++) {
      int p = inst * 256 + tid;
      int r = p >> 3;
      int c = (p & 7) ^ (r & 7);
      gl_lds16(A + (size_t)(m0 + r) * HID + k0 + c * 8, buf + p * 16);
    }
#pragma unroll
    for (int inst = 0; inst < BN / 32; inst++) {
      int p = inst * 256 + tid;
      int r = p >> 3;
      int c = (p & 7) ^ (r & 7);
      gl_lds16(Bt + (size_t)(n0 + r) * HID + k0 + c * 8, buf + BM * 128 + p * 16);
    }
  };

  auto compute = [&](const char* buf) {
#pragma unroll
    for (int kk = 0; kk < 2; kk++) {
      short8 af[RI], bf[RJ];
#pragma unroll
      for (int i = 0; i < RI; i++) {
        int ra = wm * (BM / 2) + i * 16 + l15;
        af[i] = *(const short8*)(buf + ra * 128 + (((kk * 4 + quad) ^ (ra & 7)) * 16));
      }
#pragma unroll
      for (int j = 0; j < RJ; j++) {
        int rb = wn * (BN / 2) + j * 16 + l15;
        bf[j] = *(const short8*)(buf + BM * 128 + rb * 128 + (((kk * 4 + quad) ^ (rb & 7)) * 16));
      }
#pragma unroll
      for (int i = 0; i < RI; i++)
#pragma unroll
        for (int j = 0; j < RJ; j++)
          acc[i][j] = MFMA32(af[i], bf[j], acc[i][j]);
    }
  };

  if (DBUF) {
    constexpr int NLD = BM / 32 + BN / 32;  // vmem loads per thread per tile
    issue(0, lds);
#pragma unroll 1
    for (int t = 0; t < HID / 64; t++) {
      if (t < HID / 64 - 1) {
        issue((t + 1) * 64, lds + ((t + 1) & 1) * TILE);
        asm volatile("s_waitcnt vmcnt(%0)" ::"i"(NLD) : "memory");
      } else {
        asm volatile("s_waitcnt vmcnt(0)" ::: "memory");
      }
      __builtin_amdgcn_s_barrier();
      asm volatile("" ::: "memory");
      compute(lds + (t & 1) * TILE);
      asm volatile("" ::: "memory");
      __builtin_amdgcn_s_barrier();
    }
  } else {
    for (int k0 = 0; k0 < HID; k0 += 64) {
      __syncthreads();
      issue(k0, lds);
      __syncthreads();
      compute(lds);
    }
  }

  if (TRANS_EP && mode == 2) {
    short* eb = (short*)lds;
    __syncthreads();
#pragma unroll
    for (int j = 0; j < RJ; j++) {
      int nl = wn * (BN / 2) + j * 16 + l15;
      float bsv = bias[n0 + nl];
#pragma unroll
      for (int i = 0; i < RI; i++)
#pragma unroll
        for (int r = 0; r < 4; r++) {
          int ml = wm * (BM / 2) + i * 16 + quad * 4 + r;
          eb[nl * VPS + ml] = f2bf(acc[i][j][r] + bsv);
        }
    }
    __syncthreads();
    // compacted column scatter: s -> s' = cidx[s] (drop masked)
    int row = tid >> 1, half = tid & 1;
    int n = n0 + row, h = n >> 6, d = n & 63;
    int b = m0 >> 11;
    short* dsth = outVt + ((size_t)(b * NHEADS + h) * HDIM + d) * S_LEN;
    const short* src = eb + row * VPS + half * 64;
    const short* cb = cidx + b * S_LEN + (m0 & 2047) + half * 64;
#pragma unroll 8
    for (int j = 0; j < 64; j++) {
      int sp = cb[j];
      if (sp >= 0) dsth[sp] = src[j];
    }
    return;
  }

#pragma unroll
  for (int i = 0; i < RI; i++) {
#pragma unroll
    for (int j = 0; j < RJ; j++) {
      int n = n0 + wn * (BN / 2) + j * 16 + l15;
      float bsv = bias[n];
#pragma unroll
      for (int r = 0; r < 4; r++) {
        int m = m0 + wm * (BM / 2) + i * 16 + quad * 4 + r;
        float val = acc[i][j][r] + bsv;
        if (mode == 3) {
          outF[(size_t)m * HID + n] = val;
        } else {
          int b = m >> 11, s = m & 2047, h = n >> 6, d = n & 63;
          short u = f2bf((mode == 1) ? val * SCALE_L2E : val);
          if (mode == 0) {
            outQ[((size_t)(b * NHEADS + h) * S_LEN + s) * HDIM + d] = u;
          } else {
            int sp = cidx[b * S_LEN + s];  // compact row (drop masked)
            if (sp >= 0)
              outK[((size_t)(b * NHEADS + h) * S_LEN + sp) * HDIM + d] = u;
          }
        }
      }
    }
  }
}

// ---------------- fused attention: 2q x 2k hybrid waves, KVBLK=64, DBUF ----------
// grid (S/64, NH, B), block 256 = 4 waves. Block owns 64 queries. Wave w:
// qhalf=w&1 -> queries [qhalf*32, +32); khalf=w>>1 -> keys [khalf*32, +32) of
// each 64-key tile. Keys are COMPACTED (masked keys dropped): loop runs to
// nkpad[b] (~half of S_LEN); compact bias maskc = 0 (real) / -14427 (pad).
// QK^T computed transposed (C=K*Q^T) so the 16x16 C-layout IS the 16x16x16
// A-layout of P for PV. K pre-scaled by log2e/8; acc init = bias -> bare exp2.
// Epilogue: pairwise (khalf) O/lp reduction through LDS.
// Tripwire: WRITE_SIZE ~8MB, VGPR ~56 arch, LDS_Block_Size 36864.
#define AT_DB 16384    // per-buffer stride: K 8KB + V 8KB
#define AT_VOFF 8192   // V offset within a buffer
#define ALDS_M 32768   // 4KB: compact bias bf16 [2048] (reused for lrow partials)

__device__ __forceinline__ float* buf_addr(float* base, int row, int col) {
  return base + row * 64 + ((((col >> 2) ^ (row & 15)) << 2) | (col & 3));
}

__global__ __launch_bounds__(256, 4) void attn(const short* __restrict__ Qb,
                                               const short* __restrict__ Kb,
                                               const short* __restrict__ Vt,
                                               const short* __restrict__ maskc,
                                               const int* __restrict__ nkinfo,
                                               short* __restrict__ ctx) {
  __shared__ __align__(16) char lds[36864];
  const int tid = threadIdx.x, lane = tid & 63, w = tid >> 6;
  const int quad = lane >> 4, l15 = lane & 15;
  const int qhalf = w & 1, khalf = w >> 1;
  const int h = blockIdx.y, b = blockIdx.z, bh = b * NHEADS + h;
  const short* Qh = Qb + (size_t)bh * S_LEN * HDIM;
  const short* Kh = Kb + (size_t)bh * S_LEN * HDIM;
  const short* Vh = Vt + (size_t)bh * HDIM * S_LEN;
  const short* mbase = maskc + b * S_LEN;
  const int qb0 = blockIdx.x * 64;
  const int nkp = nkinfo[b];  // compact key count, multiple of 64

  // stage a 64-key K tile [64k][64d] + V^T tile [64d][64k] into dbuf half
  auto issueKV = [&](int kb, int bufi) {
    char* base = lds + bufi * AT_DB;
#pragma unroll
    for (int inst = 0; inst < 2; inst++) {
      int p = inst * 256 + tid;
      int r = p >> 3, c = (p & 7) ^ (r & 7);
      gl_lds16(Kh + (size_t)(kb + r) * HDIM + c * 8, base + p * 16);
      gl_lds16(Vh + (size_t)r * S_LEN + kb + c * 8, base + AT_VOFF + p * 16);
    }
  };

  // stage compact bias (4KB bf16) once; drained by the first in-loop vmcnt
  gl_lds16(mbase + tid * 8, lds + ALDS_M + tid * 16);
  // prefetch first K/V tile into buffer 0
  issueKV(0, 0);

  // Q B-frags for the wave's 2 query tiles (held in regs whole kernel)
  short8 qf[2][2];
#pragma unroll
  for (int qt = 0; qt < 2; qt++)
#pragma unroll
    for (int kk = 0; kk < 2; kk++)
      qf[qt][kk] = *(const short8*)(Qh + (size_t)(qb0 + qhalf * 32 + qt * 16 + l15) * HDIM + kk * 32 + quad * 8);

  float4v o[2][4];
#pragma unroll
  for (int qt = 0; qt < 2; qt++)
#pragma unroll
    for (int nd = 0; nd < 4; nd++) o[qt][nd] = (float4v)0.0f;
  float lp[2] = {0.0f, 0.0f};

#pragma unroll 1
  for (int kb = 0; kb < nkp; kb += 64) {
    const int cur = (kb >> 6) & 1;
    const char* base = lds + cur * AT_DB;
    if (kb + 64 < nkp) {
      issueKV(kb + 64, cur ^ 1);
      asm volatile("s_waitcnt vmcnt(%0)" ::"i"(4) : "memory");
    } else {
      asm volatile("s_waitcnt vmcnt(0)" ::: "memory");
    }
    __builtin_amdgcn_s_barrier();
    asm volatile("" ::: "memory");

#pragma unroll
    for (int mt = 0; mt < 2; mt++) {
      // V B-frags (16x16x16): n=d=nd*16+l15, k=key=khalf*32+mt*16+quad*4+j
      short4v bvf[4];
      {
        int ch = khalf * 4 + mt * 2 + (quad >> 1);
        int sub = (quad & 1) * 8;
#pragma unroll
        for (int nd = 0; nd < 4; nd++) {
          int rv = nd * 16 + l15;
          bvf[nd] = *(const short4v*)(base + AT_VOFF + rv * 128 + ((ch ^ (rv & 7)) * 16) + sub);
        }
      }
      int rk = khalf * 32 + mt * 16 + l15;
      short8 ka0 = *(const short8*)(base + rk * 128 + ((quad ^ (rk & 7)) * 16));
      short8 ka1 = *(const short8*)(base + rk * 128 + (((4 + quad) ^ (rk & 7)) * 16));
      // bias: bf16 -> fp32 (4 keys for this quad)
      float4v mbv;
      {
        int midx = kb + khalf * 32 + mt * 16 + quad * 4;
        short4v ms = *(const short4v*)(lds + ALDS_M + midx * 2);
#pragma unroll
        for (int r = 0; r < 4; r++)
          mbv[r] = __uint_as_float(((uint32_t)(uint16_t)ms[r]) << 16);
      }
#pragma unroll
      for (int qt = 0; qt < 2; qt++) {
        float4v c = mbv;  // acc init = bias (exp2 domain); K pre-scaled
        c = MFMA32(ka0, qf[qt][0], c);  // C[key][q]
        c = MFMA32(ka1, qf[qt][1], c);
        float4v ev;
#pragma unroll
        for (int r = 0; r < 4; r++) ev[r] = __builtin_amdgcn_exp2f(c[r]);
        lp[qt] += (ev[0] + ev[1]) + (ev[2] + ev[3]);
        short4v ap = pack_bf16x4(ev);
#pragma unroll
        for (int nd = 0; nd < 4; nd++) o[qt][nd] = MFMA16(ap, bvf[nd], o[qt][nd]);
      }
    }
    asm volatile("" ::: "memory");
    __builtin_amdgcn_s_barrier();
  }

  // ---- epilogue: pairwise (khalf) O + lrow reduction through LDS ----
#pragma unroll
  for (int qt = 0; qt < 2; qt++) {
    lp[qt] += __shfl_xor(lp[qt], 16, 64);
    lp[qt] += __shfl_xor(lp[qt], 32, 64);
  }
  float* lrowS = (float*)(lds + ALDS_M);  // [4][32] fp32 partials (bias dead now)
  float* bufP = (float*)(lds + qhalf * 8192);  // per-pair 32q x 64d fp32
  if (quad == 0) {
#pragma unroll
    for (int qt = 0; qt < 2; qt++) lrowS[w * 32 + qt * 16 + l15] = lp[qt];
  }
  if (khalf == 1) {
#pragma unroll
    for (int qt = 0; qt < 2; qt++)
#pragma unroll
      for (int nd = 0; nd < 4; nd++)
#pragma unroll
        for (int r = 0; r < 4; r++)
          *buf_addr(bufP, qt * 16 + quad * 4 + r, nd * 16 + l15) = o[qt][nd][r];
  }
  __syncthreads();
  if (khalf == 0) {
#pragma unroll
    for (int qt = 0; qt < 2; qt++)
#pragma unroll
      for (int nd = 0; nd < 4; nd++)
#pragma unroll
        for (int r = 0; r < 4; r++) {
          float* p = buf_addr(bufP, qt * 16 + quad * 4 + r, nd * 16 + l15);
          *p = *p + o[qt][nd][r];
        }
  }
  __syncthreads();
  int row = w * 16 + l15;  // query within block, 0..63
  float ls = lrowS[row] + lrowS[64 + row];
  float inv = 1.0f / ls;
  float* bufq = (float*)(lds + (row >> 5) * 8192);
  int brow = row & 31;
  short* dstp = ctx + ((size_t)(b * S_LEN + qb0 + row) * HID + h * HDIM + quad * 16);
#pragma unroll
  for (int half = 0; half < 2; half++) {
    int c0 = quad * 16 + half * 8;
    float4v x0 = *(float4v*)buf_addr(bufq, brow, c0);
    float4v x1 = *(float4v*)buf_addr(bufq, brow, c0 + 4);
    union { short8 s; short4v h[2]; } R;
    float4v s0, s1;
#pragma unroll
    for (int i = 0; i < 4; i++) { s0[i] = x0[i] * inv; s1[i] = x1[i] * inv; }
    R.h[0] = pack_bf16x4(s0);
    R.h[1] = pack_bf16x4(s1);
    *(short8*)(dstp + half * 8) = R.s;
  }
}

extern "C" void kernel_launch(void* const* d_in, const int* in_sizes, int n_in,
                              void* d_out, int out_size, void* d_ws, size_t ws_size,
                              hipStream_t stream) {
  const float* hs = (const float*)d_in[0];
  const int* mask = (const int*)d_in[1];
  const float* Wq = (const float*)d_in[2];
  const float* bq = (const float*)d_in[3];
  const float* Wk = (const float*)d_in[4];
  const float* bk = (const float*)d_in[5];
  const float* Wv = (const float*)d_in[6];
  const float* bv = (const float*)d_in[7];
  const float* Wo = (const float*)d_in[8];
  const float* bo = (const float*)d_in[9];
  float* out = (float*)d_out;
  char* ws = (char*)d_ws;

  short* XBF = (short*)(ws);
  short* CTX = (short*)(ws);
  short* WT  = (short*)(ws + (size_t)(8u << 20));
  short* QB  = (short*)(ws + (size_t)(16u << 20));
  short* KB  = (short*)(ws + (size_t)(24u << 20));
  short* VTt = (short*)(ws + (size_t)(32u << 20));
  short* MBc = (short*)(ws + (size_t)(40u << 20));                  // 4KB compact bias
  short* CIDX = (short*)(ws + (size_t)(40u << 20) + (64u << 10));   // 8KB int16
  int*   NKI  = (int*)(ws + (size_t)(40u << 20) + (128u << 10));    // nkpad per batch

  prep_cast<<<4096, 256, 0, stream>>>(hs, XBF);
  prep_idx<<<1, 256, 0, stream>>>(mask, MBc, CIDX, NKI, KB, VTt);
  prep_transpose<<<dim3(16, 16, 4), 256, 0, stream>>>(Wq, Wk, Wv, Wo, WT);
  gemm_bt<128, 128, true, true><<<dim3(32, 8, 3), 256, 0, stream>>>(XBF, WT, bq, bk, bv, bo, QB, KB, VTt, nullptr, CIDX, 0);
  attn<<<dim3(32, NHEADS, BATCH), 256, 0, stream>>>(QB, KB, VTt, MBc, NKI, CTX);
  gemm_bt<64, 128, false, true><<<dim3(64, 8, 1), 256, 0, stream>>>(CTX, WT, bq, bk, bv, bo, nullptr, nullptr, nullptr, out, nullptr, 3);
}

// Round 8
// 175.586 us; speedup vs baseline: 1.1403x; 1.1403x over previous
//
#include <hip/hip_runtime.h>
#include <stdint.h>
#include <stddef.h>

#define S_LEN 2048
#define BATCH 2
#define HID 1024
#define NHEADS 16
#define HDIM 64

typedef __attribute__((ext_vector_type(8))) short short8;
typedef __attribute__((ext_vector_type(4))) short short4v;
typedef __attribute__((ext_vector_type(4))) float float4v;

#define MFMA32(a, b, c) __builtin_amdgcn_mfma_f32_16x16x32_bf16((a), (b), (c), 0, 0, 0)

#if __has_builtin(__builtin_amdgcn_mfma_f32_16x16x16_bf16)
#define MFMA16(a, b, c) __builtin_amdgcn_mfma_f32_16x16x16_bf16((a), (b), (c), 0, 0, 0)
#elif __has_builtin(__builtin_amdgcn_mfma_f32_16x16x16bf16_1k)
#define MFMA16(a, b, c) __builtin_amdgcn_mfma_f32_16x16x16bf16_1k((a), (b), (c), 0, 0, 0)
#else
static __device__ __forceinline__ float4v mfma16_asm(short4v a, short4v b, float4v c) {
  asm volatile("v_mfma_f32_16x16x16_bf16 %0, %1, %2, %0" : "+v"(c) : "v"(a), "v"(b));
  return c;
}
#define MFMA16(a, b, c) mfma16_asm((a), (b), (c))
#endif

#define SCALE_L2E 0.18033688011f  // log2(e)/8 — folded into K at GEMM epilogue

__device__ __forceinline__ short f2bf(float f) {
  union { float f; uint32_t u; } v; v.f = f;
  uint32_t u = v.u;
  uint32_t r = (u + 0x7fffu + ((u >> 16) & 1u)) >> 16;
  return (short)(uint16_t)r;
}

// pack 4 fp32 -> 4 bf16 (round-half-up, v_perm; A-frag k=quad*4+j order)
__device__ __forceinline__ short4v pack_bf16x4(float4v v) {
  union { short4v s; uint32_t u[2]; } U;
  U.u[0] = __builtin_amdgcn_perm(__float_as_uint(v[1]) + 0x8000u,
                                 __float_as_uint(v[0]) + 0x8000u, 0x07060302u);
  U.u[1] = __builtin_amdgcn_perm(__float_as_uint(v[3]) + 0x8000u,
                                 __float_as_uint(v[2]) + 0x8000u, 0x07060302u);
  return U.s;
}

__device__ __forceinline__ void gl_lds16(const void* g, void* l) {
  __builtin_amdgcn_global_load_lds((const __attribute__((address_space(1))) void*)g,
                                   (__attribute__((address_space(3))) void*)l,
                                   16, 0, 0);
}

// ---------------- prep: cast X to bf16 ----------------
__global__ __launch_bounds__(256) void prep_cast(const float* __restrict__ x,
                                                 short* __restrict__ xbf) {
  int gid = blockIdx.x * 256 + threadIdx.x;
  const float4v* src = (const float4v*)x;
  float4v v = src[gid];
  short4v o;
  o[0] = f2bf(v[0]); o[1] = f2bf(v[1]); o[2] = f2bf(v[2]); o[3] = f2bf(v[3]);
  ((short4v*)xbf)[gid] = o;
}

// ---------------- prep: mask scan (index build only, no scatter fills) ----------
// iidx[b][s'] = original s of the s'-th unmasked key; maskc[b][s'] = 0 (real)
// or -14427 bf16 (pad/unused -> exp2 underflows to exact 0);
// nkinfo[b] = nkpad (mult of 64), nkinfo[2+b] = nk.
__global__ __launch_bounds__(256) void prep_idx(const int* __restrict__ mask,
                                                short* __restrict__ maskc,
                                                short* __restrict__ iidx,
                                                int* __restrict__ nkinfo) {
  __shared__ int sc[256];
  const int t = threadIdx.x;
  const short neg = f2bf(-14426.9504f);
  for (int b = 0; b < BATCH; b++) {
    int m[8]; int lc = 0;
    const int* mb = mask + b * S_LEN + t * 8;
#pragma unroll
    for (int j = 0; j < 8; j++) { m[j] = mb[j]; lc += (m[j] == 0); }
    sc[t] = lc;
    __syncthreads();
#pragma unroll
    for (int off = 1; off < 256; off <<= 1) {
      int u = (t >= off) ? sc[t - off] : 0;
      int v = sc[t];
      __syncthreads();
      sc[t] = u + v;
      __syncthreads();
    }
    int excl = sc[t] - lc;
    int nk = sc[255];
    if (t == 0) { nkinfo[b] = (nk + 63) & ~63; nkinfo[2 + b] = nk; }
    int run = excl;
#pragma unroll
    for (int j = 0; j < 8; j++) {
      if (m[j] == 0) { iidx[b * S_LEN + run] = (short)(t * 8 + j); run++; }
    }
    for (int i = t; i < S_LEN; i += 256)
      maskc[b * S_LEN + i] = (i < nk) ? (short)0 : neg;
    __syncthreads();
  }
}

// ---------------- prep: compact X rows for the K/V GEMMs ----------------
// XC[b, s', :] = XBF[b, iidx[s'], :] for s' < nk; zeros for s' >= nk.
// Row-contiguous on both sides -> fully vectorized. 512 blocks x 8 rows.
__global__ __launch_bounds__(256) void prep_compact(const short* __restrict__ xbf,
                                                    const short* __restrict__ iidx,
                                                    const int* __restrict__ nkinfo,
                                                    short* __restrict__ xc) {
  const int t = threadIdx.x;
  const int b = blockIdx.x >> 8;          // 256 blocks per batch
  const int row = (blockIdx.x & 255) * 8 + (t >> 5);
  const int ch = (t & 31) * 32;           // 32 shorts (64B) per thread
  const int nk = nkinfo[2 + b];
  short* dst = xc + ((size_t)b * S_LEN + row) * HID + ch;
  if (row < nk) {
    const short* src = xbf + ((size_t)b * S_LEN + iidx[b * S_LEN + row]) * HID + ch;
#pragma unroll
    for (int k = 0; k < 4; k++) *(short8*)(dst + k * 8) = *(const short8*)(src + k * 8);
  } else {
#pragma unroll
    for (int k = 0; k < 4; k++) *(short8*)(dst + k * 8) = (short8)0;
  }
}

// ---------------- prep: transpose+cast the four weight matrices ----------------
__global__ __launch_bounds__(256) void prep_transpose(const float* __restrict__ w0,
                                                      const float* __restrict__ w1,
                                                      const float* __restrict__ w2,
                                                      const float* __restrict__ w3,
                                                      short* __restrict__ wt) {
  __shared__ short lds[64 * 66];
  int z = blockIdx.z;
  const float* w = (z == 0) ? w0 : (z == 1) ? w1 : (z == 2) ? w2 : w3;
  short* out = wt + (size_t)z * HID * HID;
  int k0 = blockIdx.x * 64, n0 = blockIdx.y * 64;
  int lane = threadIdx.x & 63, wrp = threadIdx.x >> 6;
#pragma unroll
  for (int i = 0; i < 16; i++) {
    int rr = wrp + i * 4;
    lds[lane * 66 + rr] = f2bf(w[(size_t)(k0 + rr) * HID + n0 + lane]);
  }
  __syncthreads();
#pragma unroll
  for (int i = 0; i < 16; i++) {
    int nn = wrp + i * 4;
    out[(size_t)(n0 + nn) * HID + k0 + lane] = lds[nn * 66 + lane];
  }
}

// ---------------- GEMM: C[M x N] = A[M x K] * Bt[N x K]^T + bias ----------------
// mode 0: Q from A0=XBF (original rows, bf16 [b,h,s,d]).
// mode 1: K from AC=XC (COMPACT rows; pre-scaled by log2e/8); dense vector write.
// mode 2: Vt from AC=XC (compact cols via LDS transpose); dense vector write.
// mode 3: fp32 row-major (out projection), A0=CTX.
// Modes 1/2: blocks with (m0&2047) >= nkpad[b] early-exit (~45% work cut).
// DBUF: raw-barrier double-buffer, counted vmcnt across the barrier.
#define VPS 136  // Vt epilogue LDS row stride (shorts): 272B, 16B-aligned
template <int BM, int BN, bool TRANS_EP, bool DBUF>
__global__ __launch_bounds__(256) void gemm_bt(const short* __restrict__ A0,
                                               const short* __restrict__ AC,
                                               const short* __restrict__ WTbase,
                                               const float* __restrict__ bq,
                                               const float* __restrict__ bk,
                                               const float* __restrict__ bv,
                                               const float* __restrict__ bo,
                                               short* __restrict__ outQ,
                                               short* __restrict__ outK,
                                               short* __restrict__ outVt,
                                               float* __restrict__ outF,
                                               const int* __restrict__ nki,
                                               int mode_base) {
  constexpr int RI = BM / 32;
  constexpr int RJ = BN / 32;
  constexpr int TILE = BM * 128 + BN * 128;  // one staging tile (A+B)
  constexpr int LSZ1 = DBUF ? TILE * 2 : TILE;
  constexpr int LSZ = (TRANS_EP && LSZ1 < 128 * VPS * 2) ? 128 * VPS * 2 : LSZ1;
  __shared__ __align__(16) char lds[LSZ];
  const int tid = threadIdx.x;
  const int lane = tid & 63, w = tid >> 6;
  const int wm = w & 1, wn = w >> 1;
  const int quad = lane >> 4, l15 = lane & 15;
  const int mode = mode_base + blockIdx.z;
  const int m0 = blockIdx.x * BM, n0 = blockIdx.y * BN;
  if ((mode == 1 || mode == 2) && (m0 & 2047) >= nki[m0 >> 11]) return;
  const short* A = (mode == 1 || mode == 2) ? AC : A0;
  const short* Bt = WTbase + (size_t)mode * HID * HID;
  const float* bias = (mode == 0) ? bq : (mode == 1) ? bk : (mode == 2) ? bv : bo;

  float4v acc[RI][RJ];
#pragma unroll
  for (int i = 0; i < RI; i++)
#pragma unroll
    for (int j = 0; j < RJ; j++) acc[i][j] = (float4v)0.0f;

  // stage one 64-K tile (BM/32 + BN/32 gl_lds16 per thread)
  auto issue = [&](int k0, char* buf) {
#pragma unroll
    for (int inst = 0; inst < BM / 32; inst++) {
      int p = inst * 256 + tid;
      int r = p >> 3;
      int c = (p & 7) ^ (r & 7);
      gl_lds16(A + (size_t)(m0 + r) * HID + k0 + c * 8, buf + p * 16);
    }
#pragma unroll
    for (int inst = 0; inst < BN / 32; inst++) {
      int p = inst * 256 + tid;
      int r = p >> 3;
      int c = (p & 7) ^ (r & 7);
      gl_lds16(Bt + (size_t)(n0 + r) * HID + k0 + c * 8, buf + BM * 128 + p * 16);
    }
  };

  auto compute = [&](const char* buf) {
#pragma unroll
    for (int kk = 0; kk < 2; kk++) {
      short8 af[RI], bf[RJ];
#pragma unroll
      for (int i = 0; i < RI; i++) {
        int ra = wm * (BM / 2) + i * 16 + l15;
        af[i] = *(const short8*)(buf + ra * 128 + (((kk * 4 + quad) ^ (ra & 7)) * 16));
      }
#pragma unroll
      for (int j = 0; j < RJ; j++) {
        int rb = wn * (BN / 2) + j * 16 + l15;
        bf[j] = *(const short8*)(buf + BM * 128 + rb * 128 + (((kk * 4 + quad) ^ (rb & 7)) * 16));
      }
#pragma unroll
      for (int i = 0; i < RI; i++)
#pragma unroll
        for (int j = 0; j < RJ; j++)
          acc[i][j] = MFMA32(af[i], bf[j], acc[i][j]);
    }
  };

  if (DBUF) {
    constexpr int NLD = BM / 32 + BN / 32;  // vmem loads per thread per tile
    issue(0, lds);
#pragma unroll 1
    for (int t = 0; t < HID / 64; t++) {
      if (t < HID / 64 - 1) {
        issue((t + 1) * 64, lds + ((t + 1) & 1) * TILE);
        asm volatile("s_waitcnt vmcnt(%0)" ::"i"(NLD) : "memory");
      } else {
        asm volatile("s_waitcnt vmcnt(0)" ::: "memory");
      }
      __builtin_amdgcn_s_barrier();
      asm volatile("" ::: "memory");
      compute(lds + (t & 1) * TILE);
      asm volatile("" ::: "memory");
      __builtin_amdgcn_s_barrier();
    }
  } else {
    for (int k0 = 0; k0 < HID; k0 += 64) {
      __syncthreads();
      issue(k0, lds);
      __syncthreads();
      compute(lds);
    }
  }

  if (TRANS_EP && mode == 2) {
    short* eb = (short*)lds;
    __syncthreads();
#pragma unroll
    for (int j = 0; j < RJ; j++) {
      int nl = wn * (BN / 2) + j * 16 + l15;
      float bsv = bias[n0 + nl];
#pragma unroll
      for (int i = 0; i < RI; i++)
#pragma unroll
        for (int r = 0; r < 4; r++) {
          int ml = wm * (BM / 2) + i * 16 + quad * 4 + r;
          eb[nl * VPS + ml] = f2bf(acc[i][j][r] + bsv);
        }
    }
    __syncthreads();
    int row = tid >> 1, half = tid & 1;
    int n = n0 + row, h = n >> 6, d = n & 63;
    int b = m0 >> 11, sc = (m0 & 2047) + half * 64;  // compact col base
    short* dst = outVt + ((size_t)(b * NHEADS + h) * HDIM + d) * S_LEN + sc;
    const short* src = eb + row * VPS + half * 64;
#pragma unroll
    for (int c = 0; c < 8; c++)
      *(short8*)(dst + c * 8) = *(const short8*)(src + c * 8);
    return;
  }

#pragma unroll
  for (int i = 0; i < RI; i++) {
#pragma unroll
    for (int j = 0; j < RJ; j++) {
      int n = n0 + wn * (BN / 2) + j * 16 + l15;
      float bsv = bias[n];
#pragma unroll
      for (int r = 0; r < 4; r++) {
        int m = m0 + wm * (BM / 2) + i * 16 + quad * 4 + r;
        float val = acc[i][j][r] + bsv;
        if (mode == 3) {
          outF[(size_t)m * HID + n] = val;
        } else {
          int b = m >> 11, s = m & 2047, h = n >> 6, d = n & 63;  // s compact for mode 1
          if (mode == 1) val *= SCALE_L2E;
          short u = f2bf(val);
          if (mode == 0)
            outQ[((size_t)(b * NHEADS + h) * S_LEN + s) * HDIM + d] = u;
          else
            outK[((size_t)(b * NHEADS + h) * S_LEN + s) * HDIM + d] = u;
        }
      }
    }
  }
}

// ---------------- fused attention: 2q x 2k hybrid waves, KVBLK=64, DBUF ----------
// grid (S/64, NH, B), block 256 = 4 waves. Block owns 64 queries. Wave w:
// qhalf=w&1 -> queries [qhalf*32, +32); khalf=w>>1 -> keys [khalf*32, +32) of
// each 64-key tile. Keys are COMPACTED (masked keys dropped): loop runs to
// nkpad[b] (~half of S_LEN); compact bias maskc = 0 (real) / -14427 (pad).
// QK^T computed transposed (C=K*Q^T) so the 16x16 C-layout IS the 16x16x16
// A-layout of P for PV. K pre-scaled by log2e/8; acc init = bias -> bare exp2.
// Epilogue: pairwise (khalf) O/lp reduction through LDS.
#define AT_DB 16384    // per-buffer stride: K 8KB + V 8KB
#define AT_VOFF 8192   // V offset within a buffer
#define ALDS_M 32768   // 4KB: compact bias bf16 [2048] (reused for lrow partials)

__device__ __forceinline__ float* buf_addr(float* base, int row, int col) {
  return base + row * 64 + ((((col >> 2) ^ (row & 15)) << 2) | (col & 3));
}

__global__ __launch_bounds__(256, 4) void attn(const short* __restrict__ Qb,
                                               const short* __restrict__ Kb,
                                               const short* __restrict__ Vt,
                                               const short* __restrict__ maskc,
                                               const int* __restrict__ nkinfo,
                                               short* __restrict__ ctx) {
  __shared__ __align__(16) char lds[36864];
  const int tid = threadIdx.x, lane = tid & 63, w = tid >> 6;
  const int quad = lane >> 4, l15 = lane & 15;
  const int qhalf = w & 1, khalf = w >> 1;
  const int h = blockIdx.y, b = blockIdx.z, bh = b * NHEADS + h;
  const short* Qh = Qb + (size_t)bh * S_LEN * HDIM;
  const short* Kh = Kb + (size_t)bh * S_LEN * HDIM;
  const short* Vh = Vt + (size_t)bh * HDIM * S_LEN;
  const short* mbase = maskc + b * S_LEN;
  const int qb0 = blockIdx.x * 64;
  const int nkp = nkinfo[b];  // compact key count, multiple of 64

  // stage a 64-key K tile [64k][64d] + V^T tile [64d][64k] into dbuf half
  auto issueKV = [&](int kb, int bufi) {
    char* base = lds + bufi * AT_DB;
#pragma unroll
    for (int inst = 0; inst < 2; inst++) {
      int p = inst * 256 + tid;
      int r = p >> 3, c = (p & 7) ^ (r & 7);
      gl_lds16(Kh + (size_t)(kb + r) * HDIM + c * 8, base + p * 16);
      gl_lds16(Vh + (size_t)r * S_LEN + kb + c * 8, base + AT_VOFF + p * 16);
    }
  };

  // stage compact bias (4KB bf16) once; drained by the first in-loop vmcnt
  gl_lds16(mbase + tid * 8, lds + ALDS_M + tid * 16);
  // prefetch first K/V tile into buffer 0
  issueKV(0, 0);

  // Q B-frags for the wave's 2 query tiles (held in regs whole kernel)
  short8 qf[2][2];
#pragma unroll
  for (int qt = 0; qt < 2; qt++)
#pragma unroll
    for (int kk = 0; kk < 2; kk++)
      qf[qt][kk] = *(const short8*)(Qh + (size_t)(qb0 + qhalf * 32 + qt * 16 + l15) * HDIM + kk * 32 + quad * 8);

  float4v o[2][4];
#pragma unroll
  for (int qt = 0; qt < 2; qt++)
#pragma unroll
    for (int nd = 0; nd < 4; nd++) o[qt][nd] = (float4v)0.0f;
  float lp[2] = {0.0f, 0.0f};

#pragma unroll 1
  for (int kb = 0; kb < nkp; kb += 64) {
    const int cur = (kb >> 6) & 1;
    const char* base = lds + cur * AT_DB;
    if (kb + 64 < nkp) {
      issueKV(kb + 64, cur ^ 1);
      asm volatile("s_waitcnt vmcnt(%0)" ::"i"(4) : "memory");
    } else {
      asm volatile("s_waitcnt vmcnt(0)" ::: "memory");
    }
    __builtin_amdgcn_s_barrier();
    asm volatile("" ::: "memory");

#pragma unroll
    for (int mt = 0; mt < 2; mt++) {
      // V B-frags (16x16x16): n=d=nd*16+l15, k=key=khalf*32+mt*16+quad*4+j
      short4v bvf[4];
      {
        int ch = khalf * 4 + mt * 2 + (quad >> 1);
        int sub = (quad & 1) * 8;
#pragma unroll
        for (int nd = 0; nd < 4; nd++) {
          int rv = nd * 16 + l15;
          bvf[nd] = *(const short4v*)(base + AT_VOFF + rv * 128 + ((ch ^ (rv & 7)) * 16) + sub);
        }
      }
      int rk = khalf * 32 + mt * 16 + l15;
      short8 ka0 = *(const short8*)(base + rk * 128 + ((quad ^ (rk & 7)) * 16));
      short8 ka1 = *(const short8*)(base + rk * 128 + (((4 + quad) ^ (rk & 7)) * 16));
      // bias: bf16 -> fp32 (4 keys for this quad)
      float4v mbv;
      {
        int midx = kb + khalf * 32 + mt * 16 + quad * 4;
        short4v ms = *(const short4v*)(lds + ALDS_M + midx * 2);
#pragma unroll
        for (int r = 0; r < 4; r++)
          mbv[r] = __uint_as_float(((uint32_t)(uint16_t)ms[r]) << 16);
      }
#pragma unroll
      for (int qt = 0; qt < 2; qt++) {
        float4v c = mbv;  // acc init = bias (exp2 domain); K pre-scaled
        c = MFMA32(ka0, qf[qt][0], c);  // C[key][q]
        c = MFMA32(ka1, qf[qt][1], c);
        float4v ev;
#pragma unroll
        for (int r = 0; r < 4; r++) ev[r] = __builtin_amdgcn_exp2f(c[r]);
        lp[qt] += (ev[0] + ev[1]) + (ev[2] + ev[3]);
        short4v ap = pack_bf16x4(ev);
#pragma unroll
        for (int nd = 0; nd < 4; nd++) o[qt][nd] = MFMA16(ap, bvf[nd], o[qt][nd]);
      }
    }
    asm volatile("" ::: "memory");
    __builtin_amdgcn_s_barrier();
  }

  // ---- epilogue: pairwise (khalf) O + lrow reduction through LDS ----
#pragma unroll
  for (int qt = 0; qt < 2; qt++) {
    lp[qt] += __shfl_xor(lp[qt], 16, 64);
    lp[qt] += __shfl_xor(lp[qt], 32, 64);
  }
  float* lrowS = (float*)(lds + ALDS_M);  // [4][32] fp32 partials (bias dead now)
  float* bufP = (float*)(lds + qhalf * 8192);  // per-pair 32q x 64d fp32
  if (quad == 0) {
#pragma unroll
    for (int qt = 0; qt < 2; qt++) lrowS[w * 32 + qt * 16 + l15] = lp[qt];
  }
  if (khalf == 1) {
#pragma unroll
    for (int qt = 0; qt < 2; qt++)
#pragma unroll
      for (int nd = 0; nd < 4; nd++)
#pragma unroll
        for (int r = 0; r < 4; r++)
          *buf_addr(bufP, qt * 16 + quad * 4 + r, nd * 16 + l15) = o[qt][nd][r];
  }
  __syncthreads();
  if (khalf == 0) {
#pragma unroll
    for (int qt = 0; qt < 2; qt++)
#pragma unroll
      for (int nd = 0; nd < 4; nd++)
#pragma unroll
        for (int r = 0; r < 4; r++) {
          float* p = buf_addr(bufP, qt * 16 + quad * 4 + r, nd * 16 + l15);
          *p = *p + o[qt][nd][r];
        }
  }
  __syncthreads();
  int row = w * 16 + l15;  // query within block, 0..63
  float ls = lrowS[row] + lrowS[64 + row];
  float inv = 1.0f / ls;
  float* bufq = (float*)(lds + (row >> 5) * 8192);
  int brow = row & 31;
  short* dstp = ctx + ((size_t)(b * S_LEN + qb0 + row) * HID + h * HDIM + quad * 16);
#pragma unroll
  for (int half = 0; half < 2; half++) {
    int c0 = quad * 16 + half * 8;
    float4v x0 = *(float4v*)buf_addr(bufq, brow, c0);
    float4v x1 = *(float4v*)buf_addr(bufq, brow, c0 + 4);
    union { short8 s; short4v h[2]; } R;
    float4v s0, s1;
#pragma unroll
    for (int i = 0; i < 4; i++) { s0[i] = x0[i] * inv; s1[i] = x1[i] * inv; }
    R.h[0] = pack_bf16x4(s0);
    R.h[1] = pack_bf16x4(s1);
    *(short8*)(dstp + half * 8) = R.s;
  }
}

extern "C" void kernel_launch(void* const* d_in, const int* in_sizes, int n_in,
                              void* d_out, int out_size, void* d_ws, size_t ws_size,
                              hipStream_t stream) {
  const float* hs = (const float*)d_in[0];
  const int* mask = (const int*)d_in[1];
  const float* Wq = (const float*)d_in[2];
  const float* bq = (const float*)d_in[3];
  const float* Wk = (const float*)d_in[4];
  const float* bk = (const float*)d_in[5];
  const float* Wv = (const float*)d_in[6];
  const float* bv = (const float*)d_in[7];
  const float* Wo = (const float*)d_in[8];
  const float* bo = (const float*)d_in[9];
  float* out = (float*)d_out;
  char* ws = (char*)d_ws;

  short* XBF = (short*)(ws);                                       // 8MB (CTX aliases)
  short* CTX = (short*)(ws);
  short* WT  = (short*)(ws + (size_t)(8u << 20));                  // 8MB
  short* QB  = (short*)(ws + (size_t)(16u << 20));                 // 8MB
  short* KB  = (short*)(ws + (size_t)(24u << 20));                 // 8MB
  short* VTt = (short*)(ws + (size_t)(32u << 20));                 // 8MB
  short* MBc = (short*)(ws + (size_t)(40u << 20));                 // 4KB compact bias
  short* IIDX = (short*)(ws + (size_t)(40u << 20) + (64u << 10));  // 8KB inverse idx
  int*   NKI  = (int*)(ws + (size_t)(40u << 20) + (128u << 10));   // [b]=nkpad,[2+b]=nk
  short* XC  = (short*)(ws + (size_t)(41u << 20));                 // 8MB compact X

  prep_cast<<<4096, 256, 0, stream>>>(hs, XBF);
  prep_idx<<<1, 256, 0, stream>>>(mask, MBc, IIDX, NKI);
  prep_compact<<<512, 256, 0, stream>>>(XBF, IIDX, NKI, XC);
  prep_transpose<<<dim3(16, 16, 4), 256, 0, stream>>>(Wq, Wk, Wv, Wo, WT);
  gemm_bt<128, 128, true, true><<<dim3(32, 8, 3), 256, 0, stream>>>(XBF, XC, WT, bq, bk, bv, bo, QB, KB, VTt, nullptr, NKI, 0);
  attn<<<dim3(32, NHEADS, BATCH), 256, 0, stream>>>(QB, KB, VTt, MBc, NKI, CTX);
  gemm_bt<64, 128, false, true><<<dim3(64, 8, 1), 256, 0, stream>>>(CTX, nullptr, WT, bq, bk, bv, bo, nullptr, nullptr, nullptr, out, nullptr, 3);
}

// Round 9
// 170.851 us; speedup vs baseline: 1.1719x; 1.0277x over previous
//
#include <hip/hip_runtime.h>
#include <stdint.h>
#include <stddef.h>

#define S_LEN 2048
#define BATCH 2
#define HID 1024
#define NHEADS 16
#define HDIM 64

typedef __attribute__((ext_vector_type(8))) short short8;
typedef __attribute__((ext_vector_type(4))) short short4v;
typedef __attribute__((ext_vector_type(4))) float float4v;

#define MFMA32(a, b, c) __builtin_amdgcn_mfma_f32_16x16x32_bf16((a), (b), (c), 0, 0, 0)

#if __has_builtin(__builtin_amdgcn_mfma_f32_16x16x16_bf16)
#define MFMA16(a, b, c) __builtin_amdgcn_mfma_f32_16x16x16_bf16((a), (b), (c), 0, 0, 0)
#elif __has_builtin(__builtin_amdgcn_mfma_f32_16x16x16bf16_1k)
#define MFMA16(a, b, c) __builtin_amdgcn_mfma_f32_16x16x16bf16_1k((a), (b), (c), 0, 0, 0)
#else
static __device__ __forceinline__ float4v mfma16_asm(short4v a, short4v b, float4v c) {
  asm volatile("v_mfma_f32_16x16x16_bf16 %0, %1, %2, %0" : "+v"(c) : "v"(a), "v"(b));
  return c;
}
#define MFMA16(a, b, c) mfma16_asm((a), (b), (c))
#endif

#define SCALE_L2E 0.18033688011f  // log2(e)/8 — folded into K at GEMM epilogue

__device__ __forceinline__ short f2bf(float f) {
  union { float f; uint32_t u; } v; v.f = f;
  uint32_t u = v.u;
  uint32_t r = (u + 0x7fffu + ((u >> 16) & 1u)) >> 16;
  return (short)(uint16_t)r;
}

// pack 4 fp32 -> 4 bf16 (round-half-up, v_perm; A-frag k=quad*4+j order)
__device__ __forceinline__ short4v pack_bf16x4(float4v v) {
  union { short4v s; uint32_t u[2]; } U;
  U.u[0] = __builtin_amdgcn_perm(__float_as_uint(v[1]) + 0x8000u,
                                 __float_as_uint(v[0]) + 0x8000u, 0x07060302u);
  U.u[1] = __builtin_amdgcn_perm(__float_as_uint(v[3]) + 0x8000u,
                                 __float_as_uint(v[2]) + 0x8000u, 0x07060302u);
  return U.s;
}

__device__ __forceinline__ void gl_lds16(const void* g, void* l) {
  __builtin_amdgcn_global_load_lds((const __attribute__((address_space(1))) void*)g,
                                   (__attribute__((address_space(3))) void*)l,
                                   16, 0, 0);
}

// ---------------- prep_all: ONE launch for cast + weight transpose + mask scan ----
// blocks [0,4096): cast X fp32->bf16.
// blocks [4096,5120): transpose+cast one 64x64 tile of Wq/Wk/Wv/Wo.
// block 5120: mask scan -> iidx (compact->orig row map, 0-filled tail),
//             maskc (0 real / -14427 pad: exp2 underflows to exact 0),
//             nkinfo[b]=nkpad (mult 64), nkinfo[2+b]=nk.
// Launch-count reduction: 7 kernels -> 4 (~10us overhead per launch).
__global__ __launch_bounds__(256) void prep_all(const float* __restrict__ x,
                                                const int* __restrict__ mask,
                                                const float* __restrict__ w0,
                                                const float* __restrict__ w1,
                                                const float* __restrict__ w2,
                                                const float* __restrict__ w3,
                                                short* __restrict__ xbf,
                                                short* __restrict__ wt,
                                                short* __restrict__ maskc,
                                                short* __restrict__ iidx,
                                                int* __restrict__ nkinfo) {
  __shared__ short slds[64 * 66];
  __shared__ int sc[256];
  const int bid = blockIdx.x, t = threadIdx.x;

  if (bid < 4096) {  // ---- cast ----
    int gid = bid * 256 + t;
    float4v v = ((const float4v*)x)[gid];
    short4v o;
    o[0] = f2bf(v[0]); o[1] = f2bf(v[1]); o[2] = f2bf(v[2]); o[3] = f2bf(v[3]);
    ((short4v*)xbf)[gid] = o;
    return;
  }

  if (bid < 5120) {  // ---- weight transpose ----
    int tt = bid - 4096;
    int z = tt >> 8;
    const float* w = (z == 0) ? w0 : (z == 1) ? w1 : (z == 2) ? w2 : w3;
    short* out = wt + (size_t)z * HID * HID;
    int k0 = (tt & 15) * 64, n0 = ((tt >> 4) & 15) * 64;
    int lane = t & 63, wrp = t >> 6;
#pragma unroll
    for (int i = 0; i < 16; i++) {
      int rr = wrp + i * 4;
      slds[lane * 66 + rr] = f2bf(w[(size_t)(k0 + rr) * HID + n0 + lane]);
    }
    __syncthreads();
#pragma unroll
    for (int i = 0; i < 16; i++) {
      int nn = wrp + i * 4;
      out[(size_t)(n0 + nn) * HID + k0 + lane] = slds[nn * 66 + lane];
    }
    return;
  }

  // ---- mask scan (single block) ----
  const short neg = f2bf(-14426.9504f);
  for (int b = 0; b < BATCH; b++) {
    int m[8]; int lc = 0;
    const int* mb = mask + b * S_LEN + t * 8;
#pragma unroll
    for (int j = 0; j < 8; j++) { m[j] = mb[j]; lc += (m[j] == 0); }
    sc[t] = lc;
    __syncthreads();
#pragma unroll
    for (int off = 1; off < 256; off <<= 1) {
      int u = (t >= off) ? sc[t - off] : 0;
      int v = sc[t];
      __syncthreads();
      sc[t] = u + v;
      __syncthreads();
    }
    int excl = sc[t] - lc;
    int nk = sc[255];
    if (t == 0) { nkinfo[b] = (nk + 63) & ~63; nkinfo[2 + b] = nk; }
    int run = excl;
#pragma unroll
    for (int j = 0; j < 8; j++) {
      if (m[j] == 0) { iidx[b * S_LEN + run] = (short)(t * 8 + j); run++; }
    }
    for (int i = nk + t; i < S_LEN; i += 256) iidx[b * S_LEN + i] = 0;  // pad -> row 0 (finite)
    for (int i = t; i < S_LEN; i += 256)
      maskc[b * S_LEN + i] = (i < nk) ? (short)0 : neg;
    __syncthreads();
  }
}

// ---------------- GEMM: C[M x N] = A[M x K] * Bt[N x K]^T + bias ----------------
// mode 0: Q from XBF rows (bf16 [b,h,s,d]).
// mode 1: K, A-rows GATHERED via iidx (compact); pre-scaled log2e/8; dense write.
// mode 2: Vt, A-rows gathered via iidx; compact cols via LDS transpose; dense write.
// mode 3: fp32 row-major (out projection).
// Modes 1/2: blocks with (m0&2047) >= nkpad[b] early-exit (~45% work cut).
// Gather is loop-invariant per thread -> hoisted to 4 scalar loads pre-K-loop.
// DBUF: raw-barrier double-buffer, counted vmcnt across the barrier.
#define VPS 136  // Vt epilogue LDS row stride (shorts): 272B, 16B-aligned
template <int BM, int BN, bool TRANS_EP, bool DBUF>
__global__ __launch_bounds__(256) void gemm_bt(const short* __restrict__ A0,
                                               const short* __restrict__ WTbase,
                                               const float* __restrict__ bq,
                                               const float* __restrict__ bk,
                                               const float* __restrict__ bv,
                                               const float* __restrict__ bo,
                                               short* __restrict__ outQ,
                                               short* __restrict__ outK,
                                               short* __restrict__ outVt,
                                               float* __restrict__ outF,
                                               const short* __restrict__ iidx,
                                               const int* __restrict__ nki,
                                               int mode_base) {
  constexpr int RI = BM / 32;
  constexpr int RJ = BN / 32;
  constexpr int TILE = BM * 128 + BN * 128;  // one staging tile (A+B)
  constexpr int LSZ1 = DBUF ? TILE * 2 : TILE;
  constexpr int LSZ = (TRANS_EP && LSZ1 < 128 * VPS * 2) ? 128 * VPS * 2 : LSZ1;
  __shared__ __align__(16) char lds[LSZ];
  const int tid = threadIdx.x;
  const int lane = tid & 63, w = tid >> 6;
  const int wm = w & 1, wn = w >> 1;
  const int quad = lane >> 4, l15 = lane & 15;
  const int mode = mode_base + blockIdx.z;
  const int m0 = blockIdx.x * BM, n0 = blockIdx.y * BN;
  const bool gath = (mode == 1 || mode == 2);
  if (gath && (m0 & 2047) >= nki[m0 >> 11]) return;
  const short* Bt = WTbase + (size_t)mode * HID * HID;
  const float* bias = (mode == 0) ? bq : (mode == 1) ? bk : (mode == 2) ? bv : bo;

  // hoisted per-inst A/B chunk pointers (A-row gather for compact modes)
  const short* aptr[BM / 32];
#pragma unroll
  for (int inst = 0; inst < BM / 32; inst++) {
    int p = inst * 256 + tid;
    int r = p >> 3, c = (p & 7) ^ (r & 7);
    int srow = m0 + r;
    if (gath) {
      int b = m0 >> 11;
      srow = b * S_LEN + (int)iidx[b * S_LEN + (m0 & 2047) + r];
    }
    aptr[inst] = A0 + (size_t)srow * HID + c * 8;
  }
  const short* bptr[BN / 32];
#pragma unroll
  for (int inst = 0; inst < BN / 32; inst++) {
    int p = inst * 256 + tid;
    int r = p >> 3, c = (p & 7) ^ (r & 7);
    bptr[inst] = Bt + (size_t)(n0 + r) * HID + c * 8;
  }

  float4v acc[RI][RJ];
#pragma unroll
  for (int i = 0; i < RI; i++)
#pragma unroll
    for (int j = 0; j < RJ; j++) acc[i][j] = (float4v)0.0f;

  // stage one 64-K tile (BM/32 + BN/32 gl_lds16 per thread)
  auto issue = [&](int k0, char* buf) {
#pragma unroll
    for (int inst = 0; inst < BM / 32; inst++) {
      int p = inst * 256 + tid;
      gl_lds16(aptr[inst] + k0, buf + p * 16);
    }
#pragma unroll
    for (int inst = 0; inst < BN / 32; inst++) {
      int p = inst * 256 + tid;
      gl_lds16(bptr[inst] + k0, buf + BM * 128 + p * 16);
    }
  };

  auto compute = [&](const char* buf) {
#pragma unroll
    for (int kk = 0; kk < 2; kk++) {
      short8 af[RI], bf[RJ];
#pragma unroll
      for (int i = 0; i < RI; i++) {
        int ra = wm * (BM / 2) + i * 16 + l15;
        af[i] = *(const short8*)(buf + ra * 128 + (((kk * 4 + quad) ^ (ra & 7)) * 16));
      }
#pragma unroll
      for (int j = 0; j < RJ; j++) {
        int rb = wn * (BN / 2) + j * 16 + l15;
        bf[j] = *(const short8*)(buf + BM * 128 + rb * 128 + (((kk * 4 + quad) ^ (rb & 7)) * 16));
      }
#pragma unroll
      for (int i = 0; i < RI; i++)
#pragma unroll
        for (int j = 0; j < RJ; j++)
          acc[i][j] = MFMA32(af[i], bf[j], acc[i][j]);
    }
  };

  if (DBUF) {
    constexpr int NLD = BM / 32 + BN / 32;  // vmem loads per thread per tile
    issue(0, lds);
#pragma unroll 1
    for (int t = 0; t < HID / 64; t++) {
      if (t < HID / 64 - 1) {
        issue((t + 1) * 64, lds + ((t + 1) & 1) * TILE);
        asm volatile("s_waitcnt vmcnt(%0)" ::"i"(NLD) : "memory");
      } else {
        asm volatile("s_waitcnt vmcnt(0)" ::: "memory");
      }
      __builtin_amdgcn_s_barrier();
      asm volatile("" ::: "memory");
      compute(lds + (t & 1) * TILE);
      asm volatile("" ::: "memory");
      __builtin_amdgcn_s_barrier();
    }
  } else {
    for (int k0 = 0; k0 < HID; k0 += 64) {
      __syncthreads();
      issue(k0, lds);
      __syncthreads();
      compute(lds);
    }
  }

  if (TRANS_EP && mode == 2) {
    short* eb = (short*)lds;
    __syncthreads();
#pragma unroll
    for (int j = 0; j < RJ; j++) {
      int nl = wn * (BN / 2) + j * 16 + l15;
      float bsv = bias[n0 + nl];
#pragma unroll
      for (int i = 0; i < RI; i++)
#pragma unroll
        for (int r = 0; r < 4; r++) {
          int ml = wm * (BM / 2) + i * 16 + quad * 4 + r;
          eb[nl * VPS + ml] = f2bf(acc[i][j][r] + bsv);
        }
    }
    __syncthreads();
    int row = tid >> 1, half = tid & 1;
    int n = n0 + row, h = n >> 6, d = n & 63;
    int b = m0 >> 11, sc = (m0 & 2047) + half * 64;  // compact col base
    short* dst = outVt + ((size_t)(b * NHEADS + h) * HDIM + d) * S_LEN + sc;
    const short* src = eb + row * VPS + half * 64;
#pragma unroll
    for (int c = 0; c < 8; c++)
      *(short8*)(dst + c * 8) = *(const short8*)(src + c * 8);
    return;
  }

#pragma unroll
  for (int i = 0; i < RI; i++) {
#pragma unroll
    for (int j = 0; j < RJ; j++) {
      int n = n0 + wn * (BN / 2) + j * 16 + l15;
      float bsv = bias[n];
#pragma unroll
      for (int r = 0; r < 4; r++) {
        int m = m0 + wm * (BM / 2) + i * 16 + quad * 4 + r;
        float val = acc[i][j][r] + bsv;
        if (mode == 3) {
          outF[(size_t)m * HID + n] = val;
        } else {
          int b = m >> 11, s = m & 2047, h = n >> 6, d = n & 63;  // s compact for mode 1
          if (mode == 1) val *= SCALE_L2E;
          short u = f2bf(val);
          if (mode == 0)
            outQ[((size_t)(b * NHEADS + h) * S_LEN + s) * HDIM + d] = u;
          else
            outK[((size_t)(b * NHEADS + h) * S_LEN + s) * HDIM + d] = u;
        }
      }
    }
  }
}

// ---------------- fused attention: 2q x 2k hybrid waves, KVBLK=64, DBUF ----------
// grid (S/64, NH, B), block 256 = 4 waves. Block owns 64 queries. Wave w:
// qhalf=w&1 -> queries [qhalf*32, +32); khalf=w>>1 -> keys [khalf*32, +32) of
// each 64-key tile. Keys are COMPACTED (masked keys dropped): loop runs to
// nkpad[b] (~half of S_LEN); compact bias maskc = 0 (real) / -14427 (pad).
// QK^T computed transposed (C=K*Q^T) so the 16x16 C-layout IS the 16x16x16
// A-layout of P for PV. K pre-scaled by log2e/8; acc init = bias -> bare exp2.
// Epilogue: pairwise (khalf) O/lp reduction through LDS.
#define AT_DB 16384    // per-buffer stride: K 8KB + V 8KB
#define AT_VOFF 8192   // V offset within a buffer
#define ALDS_M 32768   // 4KB: compact bias bf16 [2048] (reused for lrow partials)

__device__ __forceinline__ float* buf_addr(float* base, int row, int col) {
  return base + row * 64 + ((((col >> 2) ^ (row & 15)) << 2) | (col & 3));
}

__global__ __launch_bounds__(256, 4) void attn(const short* __restrict__ Qb,
                                               const short* __restrict__ Kb,
                                               const short* __restrict__ Vt,
                                               const short* __restrict__ maskc,
                                               const int* __restrict__ nkinfo,
                                               short* __restrict__ ctx) {
  __shared__ __align__(16) char lds[36864];
  const int tid = threadIdx.x, lane = tid & 63, w = tid >> 6;
  const int quad = lane >> 4, l15 = lane & 15;
  const int qhalf = w & 1, khalf = w >> 1;
  const int h = blockIdx.y, b = blockIdx.z, bh = b * NHEADS + h;
  const short* Qh = Qb + (size_t)bh * S_LEN * HDIM;
  const short* Kh = Kb + (size_t)bh * S_LEN * HDIM;
  const short* Vh = Vt + (size_t)bh * HDIM * S_LEN;
  const short* mbase = maskc + b * S_LEN;
  const int qb0 = blockIdx.x * 64;
  const int nkp = nkinfo[b];  // compact key count, multiple of 64

  // stage a 64-key K tile [64k][64d] + V^T tile [64d][64k] into dbuf half
  auto issueKV = [&](int kb, int bufi) {
    char* base = lds + bufi * AT_DB;
#pragma unroll
    for (int inst = 0; inst < 2; inst++) {
      int p = inst * 256 + tid;
      int r = p >> 3, c = (p & 7) ^ (r & 7);
      gl_lds16(Kh + (size_t)(kb + r) * HDIM + c * 8, base + p * 16);
      gl_lds16(Vh + (size_t)r * S_LEN + kb + c * 8, base + AT_VOFF + p * 16);
    }
  };

  // stage compact bias (4KB bf16) once; drained by the first in-loop vmcnt
  gl_lds16(mbase + tid * 8, lds + ALDS_M + tid * 16);
  // prefetch first K/V tile into buffer 0
  issueKV(0, 0);

  // Q B-frags for the wave's 2 query tiles (held in regs whole kernel)
  short8 qf[2][2];
#pragma unroll
  for (int qt = 0; qt < 2; qt++)
#pragma unroll
    for (int kk = 0; kk < 2; kk++)
      qf[qt][kk] = *(const short8*)(Qh + (size_t)(qb0 + qhalf * 32 + qt * 16 + l15) * HDIM + kk * 32 + quad * 8);

  float4v o[2][4];
#pragma unroll
  for (int qt = 0; qt < 2; qt++)
#pragma unroll
    for (int nd = 0; nd < 4; nd++) o[qt][nd] = (float4v)0.0f;
  float lp[2] = {0.0f, 0.0f};

#pragma unroll 1
  for (int kb = 0; kb < nkp; kb += 64) {
    const int cur = (kb >> 6) & 1;
    const char* base = lds + cur * AT_DB;
    if (kb + 64 < nkp) {
      issueKV(kb + 64, cur ^ 1);
      asm volatile("s_waitcnt vmcnt(%0)" ::"i"(4) : "memory");
    } else {
      asm volatile("s_waitcnt vmcnt(0)" ::: "memory");
    }
    __builtin_amdgcn_s_barrier();
    asm volatile("" ::: "memory");

#pragma unroll
    for (int mt = 0; mt < 2; mt++) {
      // V B-frags (16x16x16): n=d=nd*16+l15, k=key=khalf*32+mt*16+quad*4+j
      short4v bvf[4];
      {
        int ch = khalf * 4 + mt * 2 + (quad >> 1);
        int sub = (quad & 1) * 8;
#pragma unroll
        for (int nd = 0; nd < 4; nd++) {
          int rv = nd * 16 + l15;
          bvf[nd] = *(const short4v*)(base + AT_VOFF + rv * 128 + ((ch ^ (rv & 7)) * 16) + sub);
        }
      }
      int rk = khalf * 32 + mt * 16 + l15;
      short8 ka0 = *(const short8*)(base + rk * 128 + ((quad ^ (rk & 7)) * 16));
      short8 ka1 = *(const short8*)(base + rk * 128 + (((4 + quad) ^ (rk & 7)) * 16));
      // bias: bf16 -> fp32 (4 keys for this quad)
      float4v mbv;
      {
        int midx = kb + khalf * 32 + mt * 16 + quad * 4;
        short4v ms = *(const short4v*)(lds + ALDS_M + midx * 2);
#pragma unroll
        for (int r = 0; r < 4; r++)
          mbv[r] = __uint_as_float(((uint32_t)(uint16_t)ms[r]) << 16);
      }
#pragma unroll
      for (int qt = 0; qt < 2; qt++) {
        float4v c = mbv;  // acc init = bias (exp2 domain); K pre-scaled
        c = MFMA32(ka0, qf[qt][0], c);  // C[key][q]
        c = MFMA32(ka1, qf[qt][1], c);
        float4v ev;
#pragma unroll
        for (int r = 0; r < 4; r++) ev[r] = __builtin_amdgcn_exp2f(c[r]);
        lp[qt] += (ev[0] + ev[1]) + (ev[2] + ev[3]);
        short4v ap = pack_bf16x4(ev);
#pragma unroll
        for (int nd = 0; nd < 4; nd++) o[qt][nd] = MFMA16(ap, bvf[nd], o[qt][nd]);
      }
    }
    asm volatile("" ::: "memory");
    __builtin_amdgcn_s_barrier();
  }

  // ---- epilogue: pairwise (khalf) O + lrow reduction through LDS ----
#pragma unroll
  for (int qt = 0; qt < 2; qt++) {
    lp[qt] += __shfl_xor(lp[qt], 16, 64);
    lp[qt] += __shfl_xor(lp[qt], 32, 64);
  }
  float* lrowS = (float*)(lds + ALDS_M);  // [4][32] fp32 partials (bias dead now)
  float* bufP = (float*)(lds + qhalf * 8192);  // per-pair 32q x 64d fp32
  if (quad == 0) {
#pragma unroll
    for (int qt = 0; qt < 2; qt++) lrowS[w * 32 + qt * 16 + l15] = lp[qt];
  }
  if (khalf == 1) {
#pragma unroll
    for (int qt = 0; qt < 2; qt++)
#pragma unroll
      for (int nd = 0; nd < 4; nd++)
#pragma unroll
        for (int r = 0; r < 4; r++)
          *buf_addr(bufP, qt * 16 + quad * 4 + r, nd * 16 + l15) = o[qt][nd][r];
  }
  __syncthreads();
  if (khalf == 0) {
#pragma unroll
    for (int qt = 0; qt < 2; qt++)
#pragma unroll
      for (int nd = 0; nd < 4; nd++)
#pragma unroll
        for (int r = 0; r < 4; r++) {
          float* p = buf_addr(bufP, qt * 16 + quad * 4 + r, nd * 16 + l15);
          *p = *p + o[qt][nd][r];
        }
  }
  __syncthreads();
  int row = w * 16 + l15;  // query within block, 0..63
  float ls = lrowS[row] + lrowS[64 + row];
  float inv = 1.0f / ls;
  float* bufq = (float*)(lds + (row >> 5) * 8192);
  int brow = row & 31;
  short* dstp = ctx + ((size_t)(b * S_LEN + qb0 + row) * HID + h * HDIM + quad * 16);
#pragma unroll
  for (int half = 0; half < 2; half++) {
    int c0 = quad * 16 + half * 8;
    float4v x0 = *(float4v*)buf_addr(bufq, brow, c0);
    float4v x1 = *(float4v*)buf_addr(bufq, brow, c0 + 4);
    union { short8 s; short4v h[2]; } R;
    float4v s0, s1;
#pragma unroll
    for (int i = 0; i < 4; i++) { s0[i] = x0[i] * inv; s1[i] = x1[i] * inv; }
    R.h[0] = pack_bf16x4(s0);
    R.h[1] = pack_bf16x4(s1);
    *(short8*)(dstp + half * 8) = R.s;
  }
}

extern "C" void kernel_launch(void* const* d_in, const int* in_sizes, int n_in,
                              void* d_out, int out_size, void* d_ws, size_t ws_size,
                              hipStream_t stream) {
  const float* hs = (const float*)d_in[0];
  const int* mask = (const int*)d_in[1];
  const float* Wq = (const float*)d_in[2];
  const float* bq = (const float*)d_in[3];
  const float* Wk = (const float*)d_in[4];
  const float* bk = (const float*)d_in[5];
  const float* Wv = (const float*)d_in[6];
  const float* bv = (const float*)d_in[7];
  const float* Wo = (const float*)d_in[8];
  const float* bo = (const float*)d_in[9];
  float* out = (float*)d_out;
  char* ws = (char*)d_ws;

  short* XBF = (short*)(ws);                                       // 8MB (CTX aliases)
  short* CTX = (short*)(ws);
  short* WT  = (short*)(ws + (size_t)(8u << 20));                  // 8MB
  short* QB  = (short*)(ws + (size_t)(16u << 20));                 // 8MB
  short* KB  = (short*)(ws + (size_t)(24u << 20));                 // 8MB
  short* VTt = (short*)(ws + (size_t)(32u << 20));                 // 8MB
  short* MBc = (short*)(ws + (size_t)(40u << 20));                 // 4KB compact bias
  short* IIDX = (short*)(ws + (size_t)(40u << 20) + (64u << 10));  // 8KB compact->orig
  int*   NKI  = (int*)(ws + (size_t)(40u << 20) + (128u << 10));   // [b]=nkpad,[2+b]=nk

  prep_all<<<5121, 256, 0, stream>>>(hs, mask, Wq, Wk, Wv, Wo, XBF, WT, MBc, IIDX, NKI);
  gemm_bt<128, 128, true, true><<<dim3(32, 8, 3), 256, 0, stream>>>(XBF, WT, bq, bk, bv, bo, QB, KB, VTt, nullptr, IIDX, NKI, 0);
  attn<<<dim3(32, NHEADS, BATCH), 256, 0, stream>>>(QB, KB, VTt, MBc, NKI, CTX);
  gemm_bt<64, 128, false, true><<<dim3(64, 8, 1), 256, 0, stream>>>(CTX, WT, bq, bk, bv, bo, nullptr, nullptr, nullptr, out, nullptr, nullptr, 3);
}